// Round 4
// baseline (146.465 us; speedup 1.0000x reference)
//
#include <hip/hip_runtime.h>
#include <stdint.h>

#define T_ 256
#define B_ 8
#define E_ 512
#define H_ 32
#define HD_ 16
#define EXP_ 512
#define S_ 768          // T_ + EXP_
#define M_ 2048         // T_ * B_
#define SMOOTH_ 20.0f
#define KSTR 20         // Ks/Qi row stride (bf16): 40B rows -> 2-way (free) b64 reads
#define VSTR 776        // V^T LDS row stride in qkv_proj (bf16)
#define VTH  392        // V^T half-tile stride in attn_half (bf16): 784B rows -> 2-way
#define LOG2E_ 1.44269504f
#define MB0_  (-100.988655f)   // -70 * log2e

typedef __attribute__((ext_vector_type(8)))  short bf16x8;
typedef __attribute__((ext_vector_type(4)))  float f32x4;
typedef __attribute__((ext_vector_type(16))) float f32x16;
typedef __attribute__((ext_vector_type(2)))  unsigned int uint32x2;

// single-instruction packed f32->bf16 (RNE), lo = a, hi = b
__device__ __forceinline__ unsigned int cvtpk(float a, float b)
{
    unsigned int r;
    asm("v_cvt_pk_bf16_f32 %0, %1, %2" : "=v"(r) : "v"(a), "v"(b));
    return r;
}
__device__ __forceinline__ ushort bf1(float a)   // RNE scalar
{
    unsigned int u = __float_as_uint(a);
    u = u + 0x7FFFu + ((u >> 16) & 1u);
    return (ushort)(u >> 16);
}

union U16 { uint4 u; bf16x8 v; };
union U8x2 { uint2 p[2]; bf16x8 v; };

// 40B-row loader (stride KSTR=20 bf16): two 8B reads, 2-way banks
__device__ __forceinline__ bf16x8 ld20(const ushort* base, int row, int hi)
{
    U8x2 u;
    const ushort* p = &base[row * KSTR + hi * 8];
    u.p[0] = *(const uint2*)(p);
    u.p[1] = *(const uint2*)(p + 4);
    return u.v;
}

// ---------------------------------------------------------------------------
// Kernel 1: QKV projection GEMM + expansion. One block per (b,h), 16 waves.
// Identical Phase A to v15; writes expanded K (768x16), V^T (16x768), Q
// (256x16) bf16 images to workspace instead of running attention.
// ---------------------------------------------------------------------------
__global__ __launch_bounds__(1024, 4)
void qkv_proj(const float* __restrict__ X,
              const float* __restrict__ Wq, const float* __restrict__ Wk,
              const float* __restrict__ Wv,
              const float* __restrict__ bq, const float* __restrict__ bv,
              const int* __restrict__ oc,
              ushort* __restrict__ wsK, ushort* __restrict__ wsV,
              ushort* __restrict__ wsQ)
{
    __shared__ __align__(16) char raw[87552];
    ushort* Ks  = (ushort*)(raw);            // 768*20 bf16   = 30720 B
    ushort* Vt  = (ushort*)(raw + 30720);    // 16*VSTR bf16  = 24832 B
    ushort* Qi  = (ushort*)(raw + 55552);    // 256*20 bf16   = 10240 B

    const int bh  = blockIdx.x;
    const int b   = bh & 7;        // XCD-aware: same-b blocks share an XCD L2
    const int h   = bh >> 3;
    const int tid = threadIdx.x;
    const int w   = tid >> 6;      // 0..15
    const int l   = tid & 63;

    // ======================= Phase A: QKV GEMM =======================
    const int r0 = tid >> 3;          // t-row 0..127 (also covers r0+128)
    const int c8 = tid & 7;           // 8-float chunk in the 64-k tile
    const float* Xc0 = &X[((size_t)r0 * 8 + b) * E_ + c8 * 8];
    const float* Xc1 = Xc0 + (size_t)128 * 8 * E_;

    const int wr = tid >> 3;          // valid < 48 (tid < 384)
    const bool wload = (tid < 384);   // wave-uniform (waves 0..5)
    const float* Wsel = (wr < 16) ? Wq : (wr < 32 ? Wk : Wv);
    const float* Wr = &Wsel[((size_t)(h * 16 + (wr & 15))) * E_ + c8 * 8];

    f32x4 acc[3];
#pragma unroll
    for (int m = 0; m < 3; ++m) acc[m] = (f32x4){0.f, 0.f, 0.f, 0.f};

    float4 xa0, xa1, xb0, xb1, wp0, wp1;
    xa0 = *(const float4*)&Xc0[0]; xa1 = *(const float4*)&Xc0[4];
    xb0 = *(const float4*)&Xc1[0]; xb1 = *(const float4*)&Xc1[4];
    if (wload) { wp0 = *(const float4*)&Wr[0]; wp1 = *(const float4*)&Wr[4]; }

    const int ln = l & 15;
    const int lg = l >> 4;

    for (int it = 0; it < 8; ++it) {
        ushort* Ad = (ushort*)(raw + (it & 1) * 43776);
        ushort* Bd = Ad + 18432;
        *(uint4*)&Ad[r0 * 72 + c8 * 8] =
            make_uint4(cvtpk(xa0.x, xa0.y), cvtpk(xa0.z, xa0.w),
                       cvtpk(xa1.x, xa1.y), cvtpk(xa1.z, xa1.w));
        *(uint4*)&Ad[(r0 + 128) * 72 + c8 * 8] =
            make_uint4(cvtpk(xb0.x, xb0.y), cvtpk(xb0.z, xb0.w),
                       cvtpk(xb1.x, xb1.y), cvtpk(xb1.z, xb1.w));
        if (wload)
            *(uint4*)&Bd[wr * 72 + c8 * 8] =
                make_uint4(cvtpk(wp0.x, wp0.y), cvtpk(wp0.z, wp0.w),
                           cvtpk(wp1.x, wp1.y), cvtpk(wp1.z, wp1.w));
        __syncthreads();
        if (it < 7) {
            Xc0 += 64; Xc1 += 64;
            xa0 = *(const float4*)&Xc0[0]; xa1 = *(const float4*)&Xc0[4];
            xb0 = *(const float4*)&Xc1[0]; xb1 = *(const float4*)&Xc1[4];
            if (wload) { Wr += 64; wp0 = *(const float4*)&Wr[0]; wp1 = *(const float4*)&Wr[4]; }
        }
#pragma unroll
        for (int kb = 0; kb < 2; ++kb) {
            bf16x8 af = *(const bf16x8*)&Ad[(w * 16 + ln) * 72 + kb * 32 + lg * 8];
#pragma unroll
            for (int m = 0; m < 3; ++m) {
                bf16x8 bfm = *(const bf16x8*)&Bd[(m * 16 + ln) * 72 + kb * 32 + lg * 8];
                acc[m] = __builtin_amdgcn_mfma_f32_16x16x32_bf16(af, bfm, acc[m], 0, 0, 0);
            }
        }
    }

    __syncthreads();   // buffers dead; image region may be written

    // ---- write Q/K/V images (C-layout: col=ln=d, row=lg*4+r) ----
    {
        const float bqv = bq[h * 16 + ln];
        const float bvv = bv[h * 16 + ln];
#pragma unroll
        for (int r = 0; r < 4; ++r) {
            const int t = w * 16 + lg * 4 + r;
            Qi[t * KSTR + ln] = bf1(acc[0][r] + bqv);
            Ks[t * KSTR + ln] = bf1(acc[1][r]);
            Vt[ln * VSTR + t] = bf1(acc[2][r] + bvv);
        }
    }
    __syncthreads();

    // ---- expansion rows/cols 256..767 (LDS->LDS) ----
    if (tid < 512) {
        const int j   = tid;
        const int src = oc[b * EXP_ + j];
        const ushort* sp = &Ks[src * KSTR];
        ushort* dp = &Ks[(T_ + j) * KSTR];
        uint2 k0 = *(const uint2*)(sp);
        uint2 k1 = *(const uint2*)(sp + 4);
        uint2 k2 = *(const uint2*)(sp + 8);
        uint2 k3 = *(const uint2*)(sp + 12);
        *(uint2*)(dp)      = k0;
        *(uint2*)(dp + 4)  = k1;
        *(uint2*)(dp + 8)  = k2;
        *(uint2*)(dp + 12) = k3;
    } else {
        const int j   = tid - 512;
        const int src = oc[b * EXP_ + j];
#pragma unroll
        for (int d = 0; d < 16; ++d)
            Vt[d * VSTR + T_ + j] = Vt[d * VSTR + src];
    }
    __syncthreads();

    // ---- copy images to workspace (coalesced) ----
    if (tid < 768) {
        const ushort* sp = &Ks[tid * KSTR];
        uint2 a0 = *(const uint2*)(sp);
        uint2 a1 = *(const uint2*)(sp + 4);
        uint2 a2 = *(const uint2*)(sp + 8);
        uint2 a3 = *(const uint2*)(sp + 12);
        ushort* gp = &wsK[((size_t)bh * 768 + tid) * 16];
        *(uint4*)(gp)     = make_uint4(a0.x, a0.y, a1.x, a1.y);
        *(uint4*)(gp + 8) = make_uint4(a2.x, a2.y, a3.x, a3.y);
    } else {
        const int r = tid - 768;
        const ushort* sp = &Qi[r * KSTR];
        uint2 a0 = *(const uint2*)(sp);
        uint2 a1 = *(const uint2*)(sp + 4);
        uint2 a2 = *(const uint2*)(sp + 8);
        uint2 a3 = *(const uint2*)(sp + 12);
        ushort* gp = &wsQ[((size_t)bh * 256 + r) * 16];
        *(uint4*)(gp)     = make_uint4(a0.x, a0.y, a1.x, a1.y);
        *(uint4*)(gp + 8) = make_uint4(a2.x, a2.y, a3.x, a3.y);
    }
    {
        const int d = tid >> 6;          // 0..15
        const int c = tid & 63;          // 12 cols each
        const ushort* sp = &Vt[d * VSTR + c * 12];
        uint2 v0 = *(const uint2*)(sp);
        uint2 v1 = *(const uint2*)(sp + 4);
        uint2 v2 = *(const uint2*)(sp + 8);
        ushort* gp = &wsV[(size_t)bh * 16 * 768 + d * 768 + c * 12];
        *(uint2*)(gp)     = v0;
        *(uint2*)(gp + 4) = v1;
        *(uint2*)(gp + 8) = v2;
    }
}

// ---------------------------------------------------------------------------
// Kernel 2: attention halves. One block per (b,h,sh): 512 blocks x 8 waves
// (wave = tq tile), 40KB LDS -> 2 independent blocks/CU, NO barriers after
// staging. Phase-B inner loop identical to v15 (local s indices). Writes f32
// O-partials + Z to ws; cross-half combine moves to out_gemm.
// ---------------------------------------------------------------------------
__global__ __launch_bounds__(512, 4)
void attn_half(const float* __restrict__ LAW,
               const int* __restrict__ kpm, const int* __restrict__ em,
               const ushort* __restrict__ wsK, const ushort* __restrict__ wsV,
               const ushort* __restrict__ wsQ,
               float* __restrict__ wsO, float* __restrict__ wsZ)
{
    __shared__ __align__(16) char raw[39680];
    ushort* Qi  = (ushort*)(raw);            // 256*20 bf16 = 10240 B
    ushort* Ksh = (ushort*)(raw + 10240);    // 384*20 bf16 = 15360 B
    ushort* Vth = (ushort*)(raw + 25600);    // 16*VTH bf16 = 12544 B
    float*  msf = (float*) (raw + 38144);    // 384 f32     =  1536 B

    const int bid = blockIdx.x;
    const int bh  = bid >> 1;
    const int sh  = bid & 1;
    const int b   = bh & 7;
    const int h   = bh >> 3;
    const int tid = threadIdx.x;   // 0..511
    const int w   = tid >> 6;      // 0..7 = tq
    const int l   = tid & 63;

    // ---- staging (coalesced global -> LDS) ----
    {
        const ushort* QgB = &wsQ[(size_t)bh * 256 * 16];
        const int r  = tid >> 1;
        const int hf = tid & 1;
        uint4 q = *(const uint4*)&QgB[r * 16 + hf * 8];
        ushort* qp = &Qi[r * KSTR + hf * 8];
        *(uint2*)(qp)     = make_uint2(q.x, q.y);
        *(uint2*)(qp + 4) = make_uint2(q.z, q.w);
    }
    if (tid < 384) {
        const ushort* kp = &wsK[((size_t)bh * 768 + sh * 384 + tid) * 16];
        uint4 k0 = *(const uint4*)(kp);
        uint4 k1 = *(const uint4*)(kp + 8);
        ushort* dp = &Ksh[tid * KSTR];
        *(uint2*)(dp)      = make_uint2(k0.x, k0.y);
        *(uint2*)(dp + 4)  = make_uint2(k0.z, k0.w);
        *(uint2*)(dp + 8)  = make_uint2(k1.x, k1.y);
        *(uint2*)(dp + 12) = make_uint2(k1.z, k1.w);
        const int s = sh * 384 + tid;
        const int m = (s < T_) ? kpm[b * T_ + s] : em[b * EXP_ + (s - T_)];
        msf[tid] = m ? -1.0e5f : MB0_;
    }
    {
        const int d = tid >> 5;          // 0..15
        const int c = tid & 31;          // 12 cols each
        const ushort* vp = &wsV[(size_t)bh * 16 * 768 + d * 768 + sh * 384 + c * 12];
        uint2 v0 = *(const uint2*)(vp);
        uint2 v1 = *(const uint2*)(vp + 4);
        uint2 v2 = *(const uint2*)(vp + 8);
        ushort* dp = &Vth[d * VTH + c * 12];
        *(uint2*)(dp)     = v0;
        *(uint2*)(dp + 4) = v1;
        *(uint2*)(dp + 8) = v2;
    }
    __syncthreads();

    // ---- attention loop (v15 body, local s indices; ig = sh*12 + ii) ----
    const int slane = l & 31;
    const int hi    = l >> 5;
    const int tq    = w;

    bf16x8 qf = ld20(Qi, tq * 32 + slane, hi);

    const f32x16 zero16 = {0.f,0.f,0.f,0.f,0.f,0.f,0.f,0.f,
                           0.f,0.f,0.f,0.f,0.f,0.f,0.f,0.f};
    f32x16 oacc = zero16;
    float zp0 = 0.f, zp1 = 0.f, zp2 = 0.f, zp3 = 0.f;

    const float* lawb = &LAW[((size_t)b * T_ + tq * 32 + slane) * S_ + 4 * hi];
    const int ig0 = sh * 12;

    bf16x8 kf = ld20(Ksh, slane, hi);
    float4 g0 = *(const float4*)&lawb[ig0 * 32];
    float4 g1 = *(const float4*)&lawb[ig0 * 32 + 8];
    float4 g2 = *(const float4*)&lawb[ig0 * 32 + 16];
    float4 g3 = *(const float4*)&lawb[ig0 * 32 + 24];

#pragma unroll 2
    for (int ii = 0; ii < 12; ++ii) {
        const int iin = (ii + 1 < 12) ? (ii + 1) : 0;   // clamped (dead fetch on last)

        bf16x8 vf0 = *(const bf16x8*)&Vth[(l & 15) * VTH + ii * 32 + hi * 8];
        bf16x8 vf1 = *(const bf16x8*)&Vth[(l & 15) * VTH + ii * 32 + 16 + hi * 8];
        const float4 m0 = *(const float4*)&msf[ii * 32 + 4 * hi];
        const float4 m1 = *(const float4*)&msf[ii * 32 + 8 + 4 * hi];
        const float4 m2 = *(const float4*)&msf[ii * 32 + 16 + 4 * hi];
        const float4 m3 = *(const float4*)&msf[ii * 32 + 24 + 4 * hi];

        f32x16 sc = __builtin_amdgcn_mfma_f32_32x32x16_bf16(kf, qf, zero16, 0, 0, 0);

        bf16x8 kfn = ld20(Ksh, iin * 32 + slane, hi);

        const float4 lwg[4] = {g0, g1, g2, g3};
        const float4 mbg[4] = {m0, m1, m2, m3};

#pragma unroll
        for (int ks = 0; ks < 2; ++ks) {
            float pp[8];
#pragma unroll
            for (int gi = 0; gi < 2; ++gi) {
                const int g = 2 * ks + gi;
                const float4 lw4 = lwg[g];
                const float4 mb4 = mbg[g];
                const float lwa[4] = {lw4.x, lw4.y, lw4.z, lw4.w};
                const float mba[4] = {mb4.x, mb4.y, mb4.z, mb4.w};
#pragma unroll
                for (int c = 0; c < 4; ++c) {
                    const float lwv = lwa[c];
                    const float lwK = lwv * LOG2E_;
                    const float arg = __builtin_fmaf(sc[8 * ks + 4 * gi + c], lwK,
                                      __builtin_fmaf(lwK, SMOOTH_, mba[c]));
                    const float e = __builtin_amdgcn_exp2f(arg);
                    if (c == 0) zp0 += e; else if (c == 1) zp1 += e;
                    else if (c == 2) zp2 += e; else zp3 += e;
                    pp[4 * gi + c] = e * lwv;
                }
            }
            const unsigned int cA0 = cvtpk(pp[0], pp[1]);
            const unsigned int cA2 = cvtpk(pp[2], pp[3]);
            const unsigned int cB0 = cvtpk(pp[4], pp[5]);
            const unsigned int cB2 = cvtpk(pp[6], pp[7]);
            uint32x2 s0 = __builtin_amdgcn_permlane32_swap(cA0, cB0, false, false);
            uint32x2 s1 = __builtin_amdgcn_permlane32_swap(cA2, cB2, false, false);
            U16 u;
            u.u = make_uint4(s0.x, s1.x, s0.y, s1.y);
            oacc = __builtin_amdgcn_mfma_f32_32x32x16_bf16(
                       u.v, ks ? vf1 : vf0, oacc, 0, 0, 0);
        }

        const int ign = ig0 + iin;
        g0 = *(const float4*)&lawb[ign * 32];
        g1 = *(const float4*)&lawb[ign * 32 + 8];
        g2 = *(const float4*)&lawb[ign * 32 + 16];
        g3 = *(const float4*)&lawb[ign * 32 + 24];
        kf = kfn;
    }

    float z = (zp0 + zp1) + (zp2 + zp3);
    z += __shfl_xor(z, 32);

    // ---- write O-partial (f32) + Z to ws; combine happens in out_gemm ----
    if ((l & 31) < 16) {
        const int dl = l & 15;
        float* Op = &wsO[(size_t)sh * M_ * E_ + (size_t)h * 16 + dl];
#pragma unroll
        for (int r = 0; r < 16; ++r) {
            const int t = tq * 32 + (r & 3) + 8 * (r >> 2) + 4 * hi;
            Op[(size_t)(t * 8 + b) * E_] = oacc[r];
        }
    }
    if (l < 32) {
        const int t = tq * 32 + l;
        wsZ[(size_t)sh * M_ * H_ + ((size_t)(t * 8 + b)) * H_ + h] = z;
    }
}

// ---------------------------------------------------------------------------
// out GEMM v4: A built on the fly from (O0+O1)*inv(Z0+Z1) -> bf16.
// 32x64 tiles, 512 blocks -> 2 blocks/CU, BK=128 -> 4 K-iters.
// ---------------------------------------------------------------------------
__global__ __launch_bounds__(256, 2)
void out_gemm(const float* __restrict__ wsO, const float* __restrict__ wsZ,
              const float* __restrict__ Wo, const float* __restrict__ bo,
              float* __restrict__ dst)
{
    __shared__ __align__(16) ushort sbuf[96 * 136];   // 26112 B
    ushort* As = sbuf;              // 32 rows x 128 k (stride 136)
    ushort* Bs = sbuf + 32 * 136;   // 64 rows x 128 k (stride 136)

    const int n0 = blockIdx.x * 64;
    const int m0 = blockIdx.y * 32;

    const int tid = threadIdx.x;
    const int arow = tid >> 3;          // 0..31
    const int acol = (tid & 7) * 16;    // 0..112 (one h per thread-chunk)
    const int brow = tid >> 2;          // 0..63
    const int bcol = (tid & 3) * 32;    // 0,32,64,96

    const float* O0p = &wsO[(size_t)(m0 + arow) * E_ + acol];
    const float* O1p = O0p + (size_t)M_ * E_;
    const float* Zp  = &wsZ[(size_t)(m0 + arow) * H_];
    const float* Z1p = Zp + (size_t)M_ * H_;
    const float*  Wp = &Wo[(size_t)(n0 + brow) * E_ + bcol];

    f32x4 acc[2];
    acc[0] = (f32x4){0.f, 0.f, 0.f, 0.f};
    acc[1] = (f32x4){0.f, 0.f, 0.f, 0.f};

    float4 oa0 = *(const float4*)&O0p[0];
    float4 oa1 = *(const float4*)&O0p[4];
    float4 oa2 = *(const float4*)&O0p[8];
    float4 oa3 = *(const float4*)&O0p[12];
    float4 ob0 = *(const float4*)&O1p[0];
    float4 ob1 = *(const float4*)&O1p[4];
    float4 ob2 = *(const float4*)&O1p[8];
    float4 ob3 = *(const float4*)&O1p[12];
    float  zs  = Zp[acol >> 4] + Z1p[acol >> 4];
    float4 f0 = *(const float4*)&Wp[0];
    float4 f1 = *(const float4*)&Wp[4];
    float4 f2 = *(const float4*)&Wp[8];
    float4 f3 = *(const float4*)&Wp[12];
    float4 f4 = *(const float4*)&Wp[16];
    float4 f5 = *(const float4*)&Wp[20];
    float4 f6 = *(const float4*)&Wp[24];
    float4 f7 = *(const float4*)&Wp[28];

    const int l  = tid & 63;
    const int w  = tid >> 6;
    const int wm = w & 1;          // 16-row m half
    const int wn = w >> 1;         // 32-col n half
    const int lq = l >> 4;
    const int ln = l & 15;

    for (int it = 0; it < 4; ++it) {
        __syncthreads();
        {
            const float inv = (zs > 0.f) ? 1.f / zs : 0.f;
            const float c0 = (oa0.x + ob0.x) * inv, c1 = (oa0.y + ob0.y) * inv;
            const float c2 = (oa0.z + ob0.z) * inv, c3 = (oa0.w + ob0.w) * inv;
            const float c4 = (oa1.x + ob1.x) * inv, c5 = (oa1.y + ob1.y) * inv;
            const float c6 = (oa1.z + ob1.z) * inv, c7 = (oa1.w + ob1.w) * inv;
            const float c8 = (oa2.x + ob2.x) * inv, c9 = (oa2.y + ob2.y) * inv;
            const float ca = (oa2.z + ob2.z) * inv, cb = (oa2.w + ob2.w) * inv;
            const float cc = (oa3.x + ob3.x) * inv, cd = (oa3.y + ob3.y) * inv;
            const float ce = (oa3.z + ob3.z) * inv, cf = (oa3.w + ob3.w) * inv;
            *(uint4*)&As[arow * 136 + acol] =
                make_uint4(cvtpk(c0, c1), cvtpk(c2, c3), cvtpk(c4, c5), cvtpk(c6, c7));
            *(uint4*)&As[arow * 136 + acol + 8] =
                make_uint4(cvtpk(c8, c9), cvtpk(ca, cb), cvtpk(cc, cd), cvtpk(ce, cf));
        }
        *(uint4*)&Bs[brow * 136 + bcol]      = make_uint4(cvtpk(f0.x, f0.y), cvtpk(f0.z, f0.w),
                                                          cvtpk(f1.x, f1.y), cvtpk(f1.z, f1.w));
        *(uint4*)&Bs[brow * 136 + bcol + 8]  = make_uint4(cvtpk(f2.x, f2.y), cvtpk(f2.z, f2.w),
                                                          cvtpk(f3.x, f3.y), cvtpk(f3.z, f3.w));
        *(uint4*)&Bs[brow * 136 + bcol + 16] = make_uint4(cvtpk(f4.x, f4.y), cvtpk(f4.z, f4.w),
                                                          cvtpk(f5.x, f5.y), cvtpk(f5.z, f5.w));
        *(uint4*)&Bs[brow * 136 + bcol + 24] = make_uint4(cvtpk(f6.x, f6.y), cvtpk(f6.z, f6.w),
                                                          cvtpk(f7.x, f7.y), cvtpk(f7.z, f7.w));
        __syncthreads();
        if (it < 3) {
            O0p += 128; O1p += 128; Wp += 128;
            oa0 = *(const float4*)&O0p[0];
            oa1 = *(const float4*)&O0p[4];
            oa2 = *(const float4*)&O0p[8];
            oa3 = *(const float4*)&O0p[12];
            ob0 = *(const float4*)&O1p[0];
            ob1 = *(const float4*)&O1p[4];
            ob2 = *(const float4*)&O1p[8];
            ob3 = *(const float4*)&O1p[12];
            zs  = Zp[(it + 1) * 8 + (acol >> 4)] + Z1p[(it + 1) * 8 + (acol >> 4)];
            f0 = *(const float4*)&Wp[0];
            f1 = *(const float4*)&Wp[4];
            f2 = *(const float4*)&Wp[8];
            f3 = *(const float4*)&Wp[12];
            f4 = *(const float4*)&Wp[16];
            f5 = *(const float4*)&Wp[20];
            f6 = *(const float4*)&Wp[24];
            f7 = *(const float4*)&Wp[28];
        }
#pragma unroll
        for (int kb = 0; kb < 4; ++kb) {
            bf16x8 af  = *(const bf16x8*)&As[(wm * 16 + ln) * 136 + kb * 32 + lq * 8];
            bf16x8 bv0 = *(const bf16x8*)&Bs[(wn * 32 + ln) * 136 + kb * 32 + lq * 8];
            bf16x8 bv1 = *(const bf16x8*)&Bs[(wn * 32 + 16 + ln) * 136 + kb * 32 + lq * 8];
            acc[0] = __builtin_amdgcn_mfma_f32_16x16x32_bf16(af, bv0, acc[0], 0, 0, 0);
            acc[1] = __builtin_amdgcn_mfma_f32_16x16x32_bf16(af, bv1, acc[1], 0, 0, 0);
        }
    }

    const float bo0 = bo[n0 + wn * 32 + ln];
    const float bo1 = bo[n0 + wn * 32 + 16 + ln];

    __syncthreads();
    float* Lf = (float*)sbuf;       // 32 x 68 f32 = 8704 B (aliases As)
#pragma unroll
    for (int j = 0; j < 2; ++j) {
        const float bb = j ? bo1 : bo0;
        const f32x4 a = acc[j];
#pragma unroll
        for (int r = 0; r < 4; ++r)
            Lf[(wm * 16 + lq * 4 + r) * 68 + wn * 32 + j * 16 + ln] = a[r] + bb;
    }
    __syncthreads();

    {
        const int orow = tid >> 3;          // 0..31
        const int oc8  = (tid & 7) * 8;     // 0..56
        float* dp = &dst[(size_t)(m0 + orow) * E_ + n0 + oc8];
        float4 v0 = *(const float4*)&Lf[orow * 68 + oc8];
        float4 v1 = *(const float4*)&Lf[orow * 68 + oc8 + 4];
        *(float4*)&dp[0] = v0;
        *(float4*)&dp[4] = v1;
    }
}

// ---------------------------------------------------------------------------
extern "C" void kernel_launch(void* const* d_in, const int* in_sizes, int n_in,
                              void* d_out, int out_size, void* d_ws, size_t ws_size,
                              hipStream_t stream)
{
    const float* query = (const float*)d_in[0];
    const int*   oc    = (const int*)d_in[1];
    const int*   em    = (const int*)d_in[2];
    const int*   kpm   = (const int*)d_in[3];
    const float* law   = (const float*)d_in[4];
    const float* Wq    = (const float*)d_in[5];
    const float* bq    = (const float*)d_in[6];
    const float* Wk    = (const float*)d_in[7];
    const float* Wv    = (const float*)d_in[8];
    const float* bv    = (const float*)d_in[9];
    const float* Wo    = (const float*)d_in[10];
    const float* bo    = (const float*)d_in[11];
    float* out = (float*)d_out;

    char* ws = (char*)d_ws;
    ushort* wsK = (ushort*)(ws);                      // 256*768*16*2  = 6291456
    ushort* wsV = (ushort*)(ws + 6291456);            // 256*16*768*2  = 6291456
    ushort* wsQ = (ushort*)(ws + 12582912);           // 256*256*16*2  = 2097152
    float*  wsO = (float*) (ws + 14680064);           // 2*2048*512*4  = 8388608
    float*  wsZ = (float*) (ws + 23068672);           // 2*2048*32*4   =  524288

    qkv_proj<<<B_ * H_, 1024, 0, stream>>>(query, Wq, Wk, Wv, bq, bv, oc,
                                           wsK, wsV, wsQ);

    attn_half<<<B_ * H_ * 2, 512, 0, stream>>>(law, kpm, em, wsK, wsV, wsQ,
                                               wsO, wsZ);

    dim3 go(E_ / 64, M_ / 32, 1);
    out_gemm<<<go, 256, 0, stream>>>(wsO, wsZ, Wo, bo, out);
}

// Round 5
// 144.054 us; speedup vs baseline: 1.0167x; 1.0167x over previous
//
#include <hip/hip_runtime.h>
#include <stdint.h>

#define T_ 256
#define B_ 8
#define E_ 512
#define H_ 32
#define HD_ 16
#define EXP_ 512
#define S_ 768          // T_ + EXP_
#define M_ 2048         // T_ * B_
#define SMOOTH_ 20.0f
#define KSTR 20         // Ks/Qi row stride (bf16): 40B rows -> 2-way (free) b64 reads
#define VTH  392        // V^T half-tile stride in attn_half (bf16): 784B rows -> 2-way
#define LOG2E_ 1.44269504f
#define MB0_  (-100.988655f)   // -70 * log2e

typedef __attribute__((ext_vector_type(8)))  short bf16x8;
typedef __attribute__((ext_vector_type(4)))  float f32x4;
typedef __attribute__((ext_vector_type(16))) float f32x16;
typedef __attribute__((ext_vector_type(2)))  unsigned int uint32x2;

// single-instruction packed f32->bf16 (RNE), lo = a, hi = b
__device__ __forceinline__ unsigned int cvtpk(float a, float b)
{
    unsigned int r;
    asm("v_cvt_pk_bf16_f32 %0, %1, %2" : "=v"(r) : "v"(a), "v"(b));
    return r;
}

union U16 { uint4 u; bf16x8 v; };
union U8x2 { uint2 p[2]; bf16x8 v; };

// 40B-row loader (stride KSTR=20 bf16): two 8B reads, 2-way banks
__device__ __forceinline__ bf16x8 ld20(const ushort* base, int row, int hi)
{
    U8x2 u;
    const ushort* p = &base[row * KSTR + hi * 8];
    u.p[0] = *(const uint2*)(p);
    u.p[1] = *(const uint2*)(p + 4);
    return u.v;
}

// ---------------------------------------------------------------------------
// Kernel 1: QKV projection as ONE real GEMM. C[2048][1536] = X[2048][512] *
// [Wq|Wk|Wv]^T, 64x64 tiles -> grid (24,32) = 768 blocks (3 blocks/CU; X
// staged once per m-panel instead of 32x per head). Output: three bf16
// images wsQb/wsKb/wsVb, each [m=t*8+b][512], bias applied for Q/V.
// Tile body mirrors the R0-verified out_gemm structure (72-stride LDS,
// acc[2][2] of 16x16x32).
// ---------------------------------------------------------------------------
__global__ __launch_bounds__(256, 2)
void qkv_gemm(const float* __restrict__ X,
              const float* __restrict__ Wq, const float* __restrict__ Wk,
              const float* __restrict__ Wv,
              const float* __restrict__ bq, const float* __restrict__ bv,
              ushort* __restrict__ wsQb, ushort* __restrict__ wsKb,
              ushort* __restrict__ wsVb)
{
    __shared__ __align__(16) ushort sbuf[2 * 64 * 72];   // 18432 B
    ushort* As = sbuf;
    ushort* Bs = sbuf + 64 * 72;

    const int n0 = blockIdx.x * 64;       // 0..1472
    const int m0 = blockIdx.y * 64;
    const int which = n0 >> 9;            // 0=Q, 1=K, 2=V
    const int nn = n0 & 511;              // col within the selected image
    const float* Wsel = (which == 0) ? Wq : (which == 1 ? Wk : Wv);
    ushort* outb = (which == 0) ? wsQb : (which == 1 ? wsKb : wsVb);

    const int tid  = threadIdx.x;
    const int lrow = tid >> 2;            // 0..63
    const int kq   = tid & 3;             // 16-float k-chunk

    const float* Xp = &X[(size_t)(m0 + lrow) * E_ + kq * 16];
    const float* Wp = &Wsel[(size_t)(nn + lrow) * E_ + kq * 16];

    f32x4 acc[2][2];
#pragma unroll
    for (int i = 0; i < 2; ++i)
#pragma unroll
        for (int j = 0; j < 2; ++j)
            acc[i][j] = (f32x4){0.f, 0.f, 0.f, 0.f};

    float4 a0 = *(const float4*)&Xp[0];
    float4 a1 = *(const float4*)&Xp[4];
    float4 a2 = *(const float4*)&Xp[8];
    float4 a3 = *(const float4*)&Xp[12];
    float4 f0 = *(const float4*)&Wp[0];
    float4 f1 = *(const float4*)&Wp[4];
    float4 f2 = *(const float4*)&Wp[8];
    float4 f3 = *(const float4*)&Wp[12];

    const int l  = tid & 63;
    const int w  = tid >> 6;
    const int wm = w & 1;
    const int wn = w >> 1;
    const int lq = l >> 4;
    const int ln = l & 15;

    ushort* Aw = &As[lrow * 72 + kq * 16];
    ushort* Bw = &Bs[lrow * 72 + kq * 16];

    for (int it = 0; it < 8; ++it) {
        __syncthreads();
        *(uint4*)&Aw[0] = make_uint4(cvtpk(a0.x, a0.y), cvtpk(a0.z, a0.w),
                                     cvtpk(a1.x, a1.y), cvtpk(a1.z, a1.w));
        *(uint4*)&Aw[8] = make_uint4(cvtpk(a2.x, a2.y), cvtpk(a2.z, a2.w),
                                     cvtpk(a3.x, a3.y), cvtpk(a3.z, a3.w));
        *(uint4*)&Bw[0] = make_uint4(cvtpk(f0.x, f0.y), cvtpk(f0.z, f0.w),
                                     cvtpk(f1.x, f1.y), cvtpk(f1.z, f1.w));
        *(uint4*)&Bw[8] = make_uint4(cvtpk(f2.x, f2.y), cvtpk(f2.z, f2.w),
                                     cvtpk(f3.x, f3.y), cvtpk(f3.z, f3.w));
        __syncthreads();
        if (it < 7) {
            Xp += 64; Wp += 64;
            a0 = *(const float4*)&Xp[0];
            a1 = *(const float4*)&Xp[4];
            a2 = *(const float4*)&Xp[8];
            a3 = *(const float4*)&Xp[12];
            f0 = *(const float4*)&Wp[0];
            f1 = *(const float4*)&Wp[4];
            f2 = *(const float4*)&Wp[8];
            f3 = *(const float4*)&Wp[12];
        }
#pragma unroll
        for (int kb = 0; kb < 2; ++kb) {
            bf16x8 af0 = *(const bf16x8*)&As[(32 * wm + ln) * 72 + 32 * kb + lq * 8];
            bf16x8 af1 = *(const bf16x8*)&As[(32 * wm + 16 + ln) * 72 + 32 * kb + lq * 8];
            bf16x8 bf0 = *(const bf16x8*)&Bs[(32 * wn + ln) * 72 + 32 * kb + lq * 8];
            bf16x8 bf1 = *(const bf16x8*)&Bs[(32 * wn + 16 + ln) * 72 + 32 * kb + lq * 8];
            acc[0][0] = __builtin_amdgcn_mfma_f32_16x16x32_bf16(af0, bf0, acc[0][0], 0, 0, 0);
            acc[0][1] = __builtin_amdgcn_mfma_f32_16x16x32_bf16(af0, bf1, acc[0][1], 0, 0, 0);
            acc[1][0] = __builtin_amdgcn_mfma_f32_16x16x32_bf16(af1, bf0, acc[1][0], 0, 0, 0);
            acc[1][1] = __builtin_amdgcn_mfma_f32_16x16x32_bf16(af1, bf1, acc[1][1], 0, 0, 0);
        }
    }

    float bo0 = 0.f, bo1 = 0.f;
    if (which == 0) {
        bo0 = bq[nn + 32 * wn + ln];
        bo1 = bq[nn + 32 * wn + 16 + ln];
    } else if (which == 2) {
        bo0 = bv[nn + 32 * wn + ln];
        bo1 = bv[nn + 32 * wn + 16 + ln];
    }

    __syncthreads();
    float* Lf = (float*)sbuf;            // 64 x 68 f32 = 17408 B
#pragma unroll
    for (int j = 0; j < 2; ++j) {
        const float bb = j ? bo1 : bo0;
#pragma unroll
        for (int i = 0; i < 2; ++i)
#pragma unroll
            for (int r = 0; r < 4; ++r)
                Lf[(32 * wm + 16 * i + lq * 4 + r) * 68 + 32 * wn + 16 * j + ln] =
                    acc[i][j][r] + bb;
    }
    __syncthreads();

    {
        const int orow = tid >> 3;           // 0..31 (and +32)
        const int oc8  = (tid & 7) * 8;      // 0..56
#pragma unroll
        for (int hh = 0; hh < 2; ++hh) {
            const int rr = orow + hh * 32;
            float4 v0 = *(const float4*)&Lf[rr * 68 + oc8];
            float4 v1 = *(const float4*)&Lf[rr * 68 + oc8 + 4];
            *(uint4*)&outb[(size_t)(m0 + rr) * E_ + nn + oc8] =
                make_uint4(cvtpk(v0.x, v0.y), cvtpk(v0.z, v0.w),
                           cvtpk(v1.x, v1.y), cvtpk(v1.z, v1.w));
        }
    }
}

// ---------------------------------------------------------------------------
// Kernel 2: attention halves (R4-verified body). One block per (b,h,sh):
// 512 blocks x 8 waves, 40KB LDS -> 2+ blocks/CU, no barriers after staging.
// Staging now gathers from the plain [m][512] Q/K/V images (L2-hot):
// K/V expansion (oc gather) + V transpose happen here, per block (32KB).
// ---------------------------------------------------------------------------
__global__ __launch_bounds__(512, 4)
void attn_half(const float* __restrict__ LAW,
               const int* __restrict__ kpm, const int* __restrict__ em,
               const int* __restrict__ oc,
               const ushort* __restrict__ wsQb, const ushort* __restrict__ wsKb,
               const ushort* __restrict__ wsVb,
               float* __restrict__ wsO, float* __restrict__ wsZ)
{
    __shared__ __align__(16) char raw[39680];
    ushort* Qi  = (ushort*)(raw);            // 256*20 bf16 = 10240 B
    ushort* Ksh = (ushort*)(raw + 10240);    // 384*20 bf16 = 15360 B
    ushort* Vth = (ushort*)(raw + 25600);    // 16*VTH bf16 = 12544 B
    float*  msf = (float*) (raw + 38144);    // 384 f32     =  1536 B

    const int bid = blockIdx.x;
    const int bh  = bid >> 1;
    const int sh  = bid & 1;
    const int b   = bh & 7;
    const int h   = bh >> 3;
    const int tid = threadIdx.x;   // 0..511
    const int w   = tid >> 6;      // 0..7 = tq
    const int l   = tid & 63;

    // ---- staging: gather from [m][512] images ----
    {
        const int r  = tid >> 1;         // 0..255
        const int hf = tid & 1;
        uint4 q = *(const uint4*)&wsQb[(size_t)(r * 8 + b) * E_ + h * 16 + hf * 8];
        ushort* qp = &Qi[r * KSTR + hf * 8];
        *(uint2*)(qp)     = make_uint2(q.x, q.y);
        *(uint2*)(qp + 4) = make_uint2(q.z, q.w);
    }
    if (tid < 384) {
        const int sg    = sh * 384 + tid;
        const int tsrc  = (sg < T_) ? sg : oc[b * EXP_ + (sg - T_)];
        const size_t mr = (size_t)(tsrc * 8 + b) * E_ + h * 16;
        uint4 k0 = *(const uint4*)&wsKb[mr];
        uint4 k1 = *(const uint4*)&wsKb[mr + 8];
        ushort* dp = &Ksh[tid * KSTR];
        *(uint2*)(dp)      = make_uint2(k0.x, k0.y);
        *(uint2*)(dp + 4)  = make_uint2(k0.z, k0.w);
        *(uint2*)(dp + 8)  = make_uint2(k1.x, k1.y);
        *(uint2*)(dp + 12) = make_uint2(k1.z, k1.w);
        U16 vv;
        vv.u.x = *((const uint*)&wsVb[mr]);
        vv.u.y = *((const uint*)&wsVb[mr + 2]);
        vv.u = *(const uint4*)&wsVb[mr];
        uint4 v1 = *(const uint4*)&wsVb[mr + 8];
        const ushort* ve0 = (const ushort*)&vv.u;
        const ushort* ve1 = (const ushort*)&v1;
#pragma unroll
        for (int d = 0; d < 8; ++d) Vth[d * VTH + tid] = ve0[d];
#pragma unroll
        for (int d = 0; d < 8; ++d) Vth[(d + 8) * VTH + tid] = ve1[d];
        const int m = (sg < T_) ? kpm[b * T_ + sg] : em[b * EXP_ + (sg - T_)];
        msf[tid] = m ? -1.0e5f : MB0_;
    }
    __syncthreads();

    // ---- attention loop (R4-verified; local s indices, ig = sh*12 + ii) ----
    const int slane = l & 31;
    const int hi    = l >> 5;
    const int tq    = w;

    bf16x8 qf = ld20(Qi, tq * 32 + slane, hi);

    const f32x16 zero16 = {0.f,0.f,0.f,0.f,0.f,0.f,0.f,0.f,
                           0.f,0.f,0.f,0.f,0.f,0.f,0.f,0.f};
    f32x16 oacc = zero16;
    float zp0 = 0.f, zp1 = 0.f, zp2 = 0.f, zp3 = 0.f;

    const float* lawb = &LAW[((size_t)b * T_ + tq * 32 + slane) * S_ + 4 * hi];
    const int ig0 = sh * 12;

    bf16x8 kf = ld20(Ksh, slane, hi);
    float4 g0 = *(const float4*)&lawb[ig0 * 32];
    float4 g1 = *(const float4*)&lawb[ig0 * 32 + 8];
    float4 g2 = *(const float4*)&lawb[ig0 * 32 + 16];
    float4 g3 = *(const float4*)&lawb[ig0 * 32 + 24];

#pragma unroll 2
    for (int ii = 0; ii < 12; ++ii) {
        const int iin = (ii + 1 < 12) ? (ii + 1) : 0;   // clamped (dead fetch on last)

        bf16x8 vf0 = *(const bf16x8*)&Vth[(l & 15) * VTH + ii * 32 + hi * 8];
        bf16x8 vf1 = *(const bf16x8*)&Vth[(l & 15) * VTH + ii * 32 + 16 + hi * 8];
        const float4 m0 = *(const float4*)&msf[ii * 32 + 4 * hi];
        const float4 m1 = *(const float4*)&msf[ii * 32 + 8 + 4 * hi];
        const float4 m2 = *(const float4*)&msf[ii * 32 + 16 + 4 * hi];
        const float4 m3 = *(const float4*)&msf[ii * 32 + 24 + 4 * hi];

        f32x16 sc = __builtin_amdgcn_mfma_f32_32x32x16_bf16(kf, qf, zero16, 0, 0, 0);

        bf16x8 kfn = ld20(Ksh, iin * 32 + slane, hi);

        const float4 lwg[4] = {g0, g1, g2, g3};
        const float4 mbg[4] = {m0, m1, m2, m3};

#pragma unroll
        for (int ks = 0; ks < 2; ++ks) {
            float pp[8];
#pragma unroll
            for (int gi = 0; gi < 2; ++gi) {
                const int g = 2 * ks + gi;
                const float4 lw4 = lwg[g];
                const float4 mb4 = mbg[g];
                const float lwa[4] = {lw4.x, lw4.y, lw4.z, lw4.w};
                const float mba[4] = {mb4.x, mb4.y, mb4.z, mb4.w};
#pragma unroll
                for (int c = 0; c < 4; ++c) {
                    const float lwv = lwa[c];
                    const float lwK = lwv * LOG2E_;
                    const float arg = __builtin_fmaf(sc[8 * ks + 4 * gi + c], lwK,
                                      __builtin_fmaf(lwK, SMOOTH_, mba[c]));
                    const float e = __builtin_amdgcn_exp2f(arg);
                    if (c == 0) zp0 += e; else if (c == 1) zp1 += e;
                    else if (c == 2) zp2 += e; else zp3 += e;
                    pp[4 * gi + c] = e * lwv;
                }
            }
            const unsigned int cA0 = cvtpk(pp[0], pp[1]);
            const unsigned int cA2 = cvtpk(pp[2], pp[3]);
            const unsigned int cB0 = cvtpk(pp[4], pp[5]);
            const unsigned int cB2 = cvtpk(pp[6], pp[7]);
            uint32x2 s0 = __builtin_amdgcn_permlane32_swap(cA0, cB0, false, false);
            uint32x2 s1 = __builtin_amdgcn_permlane32_swap(cA2, cB2, false, false);
            U16 u;
            u.u = make_uint4(s0.x, s1.x, s0.y, s1.y);
            oacc = __builtin_amdgcn_mfma_f32_32x32x16_bf16(
                       u.v, ks ? vf1 : vf0, oacc, 0, 0, 0);
        }

        const int ign = ig0 + iin;
        g0 = *(const float4*)&lawb[ign * 32];
        g1 = *(const float4*)&lawb[ign * 32 + 8];
        g2 = *(const float4*)&lawb[ign * 32 + 16];
        g3 = *(const float4*)&lawb[ign * 32 + 24];
        kf = kfn;
    }

    float z = (zp0 + zp1) + (zp2 + zp3);
    z += __shfl_xor(z, 32);

    // ---- write O-partial (f32) + Z to ws; combine happens in out_gemm ----
    if ((l & 31) < 16) {
        const int dl = l & 15;
        float* Op = &wsO[(size_t)sh * M_ * E_ + (size_t)h * 16 + dl];
#pragma unroll
        for (int r = 0; r < 16; ++r) {
            const int t = tq * 32 + (r & 3) + 8 * (r >> 2) + 4 * hi;
            Op[(size_t)(t * 8 + b) * E_] = oacc[r];
        }
    }
    if (l < 32) {
        const int t = tq * 32 + l;
        wsZ[(size_t)sh * M_ * H_ + ((size_t)(t * 8 + b)) * H_ + h] = z;
    }
}

// ---------------------------------------------------------------------------
// out GEMM v4 (R4-verified): A built on the fly from (O0+O1)*inv(Z0+Z1).
// 32x64 tiles, 512 blocks -> 2 blocks/CU, BK=128 -> 4 K-iters.
// ---------------------------------------------------------------------------
__global__ __launch_bounds__(256, 2)
void out_gemm(const float* __restrict__ wsO, const float* __restrict__ wsZ,
              const float* __restrict__ Wo, const float* __restrict__ bo,
              float* __restrict__ dst)
{
    __shared__ __align__(16) ushort sbuf[96 * 136];   // 26112 B
    ushort* As = sbuf;              // 32 rows x 128 k (stride 136)
    ushort* Bs = sbuf + 32 * 136;   // 64 rows x 128 k (stride 136)

    const int n0 = blockIdx.x * 64;
    const int m0 = blockIdx.y * 32;

    const int tid = threadIdx.x;
    const int arow = tid >> 3;          // 0..31
    const int acol = (tid & 7) * 16;    // 0..112 (one h per thread-chunk)
    const int brow = tid >> 2;          // 0..63
    const int bcol = (tid & 3) * 32;    // 0,32,64,96

    const float* O0p = &wsO[(size_t)(m0 + arow) * E_ + acol];
    const float* O1p = O0p + (size_t)M_ * E_;
    const float* Zp  = &wsZ[(size_t)(m0 + arow) * H_];
    const float* Z1p = Zp + (size_t)M_ * H_;
    const float*  Wp = &Wo[(size_t)(n0 + brow) * E_ + bcol];

    f32x4 acc[2];
    acc[0] = (f32x4){0.f, 0.f, 0.f, 0.f};
    acc[1] = (f32x4){0.f, 0.f, 0.f, 0.f};

    float4 oa0 = *(const float4*)&O0p[0];
    float4 oa1 = *(const float4*)&O0p[4];
    float4 oa2 = *(const float4*)&O0p[8];
    float4 oa3 = *(const float4*)&O0p[12];
    float4 ob0 = *(const float4*)&O1p[0];
    float4 ob1 = *(const float4*)&O1p[4];
    float4 ob2 = *(const float4*)&O1p[8];
    float4 ob3 = *(const float4*)&O1p[12];
    float  zs  = Zp[acol >> 4] + Z1p[acol >> 4];
    float4 f0 = *(const float4*)&Wp[0];
    float4 f1 = *(const float4*)&Wp[4];
    float4 f2 = *(const float4*)&Wp[8];
    float4 f3 = *(const float4*)&Wp[12];
    float4 f4 = *(const float4*)&Wp[16];
    float4 f5 = *(const float4*)&Wp[20];
    float4 f6 = *(const float4*)&Wp[24];
    float4 f7 = *(const float4*)&Wp[28];

    const int l  = tid & 63;
    const int w  = tid >> 6;
    const int wm = w & 1;          // 16-row m half
    const int wn = w >> 1;         // 32-col n half
    const int lq = l >> 4;
    const int ln = l & 15;

    for (int it = 0; it < 4; ++it) {
        __syncthreads();
        {
            const float inv = (zs > 0.f) ? 1.f / zs : 0.f;
            const float c0 = (oa0.x + ob0.x) * inv, c1 = (oa0.y + ob0.y) * inv;
            const float c2 = (oa0.z + ob0.z) * inv, c3 = (oa0.w + ob0.w) * inv;
            const float c4 = (oa1.x + ob1.x) * inv, c5 = (oa1.y + ob1.y) * inv;
            const float c6 = (oa1.z + ob1.z) * inv, c7 = (oa1.w + ob1.w) * inv;
            const float c8 = (oa2.x + ob2.x) * inv, c9 = (oa2.y + ob2.y) * inv;
            const float ca = (oa2.z + ob2.z) * inv, cb = (oa2.w + ob2.w) * inv;
            const float cc = (oa3.x + ob3.x) * inv, cd = (oa3.y + ob3.y) * inv;
            const float ce = (oa3.z + ob3.z) * inv, cf = (oa3.w + ob3.w) * inv;
            *(uint4*)&As[arow * 136 + acol] =
                make_uint4(cvtpk(c0, c1), cvtpk(c2, c3), cvtpk(c4, c5), cvtpk(c6, c7));
            *(uint4*)&As[arow * 136 + acol + 8] =
                make_uint4(cvtpk(c8, c9), cvtpk(ca, cb), cvtpk(cc, cd), cvtpk(ce, cf));
        }
        *(uint4*)&Bs[brow * 136 + bcol]      = make_uint4(cvtpk(f0.x, f0.y), cvtpk(f0.z, f0.w),
                                                          cvtpk(f1.x, f1.y), cvtpk(f1.z, f1.w));
        *(uint4*)&Bs[brow * 136 + bcol + 8]  = make_uint4(cvtpk(f2.x, f2.y), cvtpk(f2.z, f2.w),
                                                          cvtpk(f3.x, f3.y), cvtpk(f3.z, f3.w));
        *(uint4*)&Bs[brow * 136 + bcol + 16] = make_uint4(cvtpk(f4.x, f4.y), cvtpk(f4.z, f4.w),
                                                          cvtpk(f5.x, f5.y), cvtpk(f5.z, f5.w));
        *(uint4*)&Bs[brow * 136 + bcol + 24] = make_uint4(cvtpk(f6.x, f6.y), cvtpk(f6.z, f6.w),
                                                          cvtpk(f7.x, f7.y), cvtpk(f7.z, f7.w));
        __syncthreads();
        if (it < 3) {
            O0p += 128; O1p += 128; Wp += 128;
            oa0 = *(const float4*)&O0p[0];
            oa1 = *(const float4*)&O0p[4];
            oa2 = *(const float4*)&O0p[8];
            oa3 = *(const float4*)&O0p[12];
            ob0 = *(const float4*)&O1p[0];
            ob1 = *(const float4*)&O1p[4];
            ob2 = *(const float4*)&O1p[8];
            ob3 = *(const float4*)&O1p[12];
            zs  = Zp[(it + 1) * 8 + (acol >> 4)] + Z1p[(it + 1) * 8 + (acol >> 4)];
            f0 = *(const float4*)&Wp[0];
            f1 = *(const float4*)&Wp[4];
            f2 = *(const float4*)&Wp[8];
            f3 = *(const float4*)&Wp[12];
            f4 = *(const float4*)&Wp[16];
            f5 = *(const float4*)&Wp[20];
            f6 = *(const float4*)&Wp[24];
            f7 = *(const float4*)&Wp[28];
        }
#pragma unroll
        for (int kb = 0; kb < 4; ++kb) {
            bf16x8 af  = *(const bf16x8*)&As[(wm * 16 + ln) * 136 + kb * 32 + lq * 8];
            bf16x8 bv0 = *(const bf16x8*)&Bs[(wn * 32 + ln) * 136 + kb * 32 + lq * 8];
            bf16x8 bv1 = *(const bf16x8*)&Bs[(wn * 32 + 16 + ln) * 136 + kb * 32 + lq * 8];
            acc[0] = __builtin_amdgcn_mfma_f32_16x16x32_bf16(af, bv0, acc[0], 0, 0, 0);
            acc[1] = __builtin_amdgcn_mfma_f32_16x16x32_bf16(af, bv1, acc[1], 0, 0, 0);
        }
    }

    const float bo0 = bo[n0 + wn * 32 + ln];
    const float bo1 = bo[n0 + wn * 32 + 16 + ln];

    __syncthreads();
    float* Lf = (float*)sbuf;       // 32 x 68 f32 = 8704 B (aliases As)
#pragma unroll
    for (int j = 0; j < 2; ++j) {
        const float bb = j ? bo1 : bo0;
        const f32x4 a = acc[j];
#pragma unroll
        for (int r = 0; r < 4; ++r)
            Lf[(wm * 16 + lq * 4 + r) * 68 + wn * 32 + j * 16 + ln] = a[r] + bb;
    }
    __syncthreads();

    {
        const int orow = tid >> 3;          // 0..31
        const int oc8  = (tid & 7) * 8;     // 0..56
        float* dp = &dst[(size_t)(m0 + orow) * E_ + n0 + oc8];
        float4 v0 = *(const float4*)&Lf[orow * 68 + oc8];
        float4 v1 = *(const float4*)&Lf[orow * 68 + oc8 + 4];
        *(float4*)&dp[0] = v0;
        *(float4*)&dp[4] = v1;
    }
}

// ---------------------------------------------------------------------------
extern "C" void kernel_launch(void* const* d_in, const int* in_sizes, int n_in,
                              void* d_out, int out_size, void* d_ws, size_t ws_size,
                              hipStream_t stream)
{
    const float* query = (const float*)d_in[0];
    const int*   oc    = (const int*)d_in[1];
    const int*   em    = (const int*)d_in[2];
    const int*   kpm   = (const int*)d_in[3];
    const float* law   = (const float*)d_in[4];
    const float* Wq    = (const float*)d_in[5];
    const float* bq    = (const float*)d_in[6];
    const float* Wk    = (const float*)d_in[7];
    const float* Wv    = (const float*)d_in[8];
    const float* bv    = (const float*)d_in[9];
    const float* Wo    = (const float*)d_in[10];
    const float* bo    = (const float*)d_in[11];
    float* out = (float*)d_out;

    char* ws = (char*)d_ws;
    ushort* wsQb = (ushort*)(ws);                     // 2048*512*2 = 2097152
    ushort* wsKb = (ushort*)(ws + 2097152);           // 2097152
    ushort* wsVb = (ushort*)(ws + 4194304);           // 2097152
    float*  wsO  = (float*) (ws + 6291456);           // 2*2048*512*4 = 8388608
    float*  wsZ  = (float*) (ws + 14680064);          // 2*2048*32*4  =  524288

    dim3 gq(1536 / 64, M_ / 64, 1);
    qkv_gemm<<<gq, 256, 0, stream>>>(query, Wq, Wk, Wv, bq, bv,
                                     wsQb, wsKb, wsVb);

    attn_half<<<B_ * H_ * 2, 512, 0, stream>>>(law, kpm, em, oc,
                                               wsQb, wsKb, wsVb, wsO, wsZ);

    dim3 go(E_ / 64, M_ / 32, 1);
    out_gemm<<<go, 256, 0, stream>>>(wsO, wsZ, Wo, bo, out);
}